// Round 2
// baseline (715.428 us; speedup 1.0000x reference)
//
#include <hip/hip_runtime.h>
#include <cmath>

#define NN 4096
#define KK 32
#define DD 256
#define HH 128
#define G3 384   // 3*H

// ---------------------------------------------------------------------------
// Kernel 1: per-cluster ordered lists, per-sentence position, lengths;
// block KK computes the weight-norm scale g/||v||.
// ---------------------------------------------------------------------------
__global__ void build_order_k(const int* __restrict__ labels,
                              const float* __restrict__ lin_v,
                              const float* __restrict__ lin_g,
                              int* __restrict__ order,
                              int* __restrict__ pos,
                              int* __restrict__ len,
                              float* __restrict__ scale) {
  const int c = blockIdx.x;
  const int lane = threadIdx.x;
  if (c < KK) {
    int count = 0;
    for (int base = 0; base < NN; base += 64) {
      const int i = base + lane;
      const bool f = (labels[i] == c);
      const unsigned long long m = __ballot(f);
      const unsigned long long below = m & ((1ull << lane) - 1ull);
      if (f) {
        const int p = count + __popcll(below);
        order[c * NN + p] = i;
        pos[i] = p;
      }
      count += __popcll(m);
    }
    if (lane == 0) len[c] = count;
  } else {
    float s = 0.f;
    for (int j = lane; j < G3; j += 64) { const float v = lin_v[j]; s += v * v; }
    for (int off = 32; off; off >>= 1) s += __shfl_down(s, off);
    if (lane == 0) scale[0] = lin_g[0] / sqrtf(s);
  }
}

// ---------------------------------------------------------------------------
// Kernel 2: exclusive prefix over max(len,1) -> starts[KK+1]
// ---------------------------------------------------------------------------
__global__ void prefix_k(const int* __restrict__ len, int* __restrict__ starts) {
  if (threadIdx.x == 0) {
    int s = 0;
    for (int c = 0; c < KK; ++c) {
      starts[c] = s;
      const int l = len[c];
      s += (l > 0) ? l : 1;
    }
    starts[KK] = s;
  }
}

// ---------------------------------------------------------------------------
// Kernel 3/5: out[slot(i)][g] = bias[g] + sum_d X[i][d] * W[g][d]
// BM=128 rows x BN=64 gates, BK=16, 256 threads, 8x4 micro-tile (FMA-bound).
// slot(i) = starts[labels[i]] + pos[i] (gemm0) or identity (gemm1).
// ---------------------------------------------------------------------------
template<int DIN>
__global__ __launch_bounds__(256) void gemm_ih_k(
    const float* __restrict__ X, const float* __restrict__ W,
    const float* __restrict__ bias,
    const int* __restrict__ labels, const int* __restrict__ pos,
    const int* __restrict__ starts,            // slot map (labels!=null) or identity
    const int* __restrict__ Mtot,              // null -> M = NN
    float* __restrict__ out) {
  __shared__ float Xs[16][132];
  __shared__ float Ws[16][68];
  const int M = Mtot ? *Mtot : NN;
  const int i0 = blockIdx.x * 128;
  const int g0 = blockIdx.y * 64;
  const int t  = threadIdx.x;
  const int it = t & 15;
  const int gt = t >> 4;
  float acc[8][4] = {};
  for (int k0 = 0; k0 < DIN; k0 += 16) {
    // stage X tile: 128x16 = 512 float4, 2 per thread
#pragma unroll
    for (int l = 0; l < 2; ++l) {
      const int u = t * 2 + l;
      const int r = u >> 2;
      const int cq = u & 3;
      const int gi = i0 + r;
      float4 f = make_float4(0.f, 0.f, 0.f, 0.f);
      if (gi < M) f = *(const float4*)(X + (size_t)gi * DIN + k0 + cq * 4);
      Xs[cq * 4 + 0][r] = f.x; Xs[cq * 4 + 1][r] = f.y;
      Xs[cq * 4 + 2][r] = f.z; Xs[cq * 4 + 3][r] = f.w;
    }
    // stage W tile: 64x16 = 256 float4, 1 per thread
    {
      const int r = t >> 2;
      const int cq = t & 3;
      const float4 f = *(const float4*)(W + (size_t)(g0 + r) * DIN + k0 + cq * 4);
      Ws[cq * 4 + 0][r] = f.x; Ws[cq * 4 + 1][r] = f.y;
      Ws[cq * 4 + 2][r] = f.z; Ws[cq * 4 + 3][r] = f.w;
    }
    __syncthreads();
#pragma unroll
    for (int k = 0; k < 16; ++k) {
      float a[8], b[4];
#pragma unroll
      for (int x = 0; x < 8; ++x) a[x] = Xs[k][it * 8 + x];
#pragma unroll
      for (int y = 0; y < 4; ++y) b[y] = Ws[k][gt * 4 + y];
#pragma unroll
      for (int x = 0; x < 8; ++x)
#pragma unroll
        for (int y = 0; y < 4; ++y)
          acc[x][y] += a[x] * b[y];
    }
    __syncthreads();
  }
  const float4 bs = *(const float4*)(bias + g0 + gt * 4);
#pragma unroll
  for (int x = 0; x < 8; ++x) {
    const int gi = i0 + it * 8 + x;
    if (gi >= M) continue;
    const int slot = labels ? (starts[labels[gi]] + pos[gi]) : gi;
    float4 o;
    o.x = acc[x][0] + bs.x; o.y = acc[x][1] + bs.y;
    o.z = acc[x][2] + bs.z; o.w = acc[x][3] + bs.w;
    *(float4*)(out + (size_t)slot * G3 + g0 + gt * 4) = o;
  }
}

// ---------------------------------------------------------------------------
// Kernel 4/6: GRU recurrence. One block of 128 threads per cluster.
// Thread t owns W_hh rows t (r), t+128 (z), t+256 (n): 384 weight floats in
// VGPRs -> no hw exchange, ONE barrier per step. h double-buffered in LDS.
// xw rows are sorted (sequential), prefetched one step ahead.
// ---------------------------------------------------------------------------
__global__ __launch_bounds__(128, 1) void gru_rec_k(
    const float* __restrict__ xw,      // sorted [Mtot][384]
    const float* __restrict__ W_hh,    // [384][128]
    const float* __restrict__ b_hh,    // [384]
    const float* __restrict__ b_ih,    // fallback for empty cluster (layer0) or null
    const int* __restrict__ starts,
    const int* __restrict__ len,
    float* __restrict__ h_seq,         // sorted [Mtot][128] or null
    float* __restrict__ h_final) {     // [KK][128] or null
  const int c = blockIdx.x;
  const int t = threadIdx.x;           // 0..127
  float4 wr[32], wz[32], wn[32];
  {
    const float4* Wr = (const float4*)(W_hh + (size_t)t * HH);
    const float4* Wz = (const float4*)(W_hh + (size_t)(t + HH) * HH);
    const float4* Wn = (const float4*)(W_hh + (size_t)(t + 2 * HH) * HH);
#pragma unroll
    for (int q = 0; q < 32; ++q) { wr[q] = Wr[q]; wz[q] = Wz[q]; wn[q] = Wn[q]; }
  }
  const float br = b_hh[t], bz = b_hh[HH + t], bn = b_hh[2 * HH + t];
  const int L = len[c];
  const int start = starts[c];
  const int Lr = (L > 0) ? L : 1;
  __shared__ __align__(16) float hbuf[2][HH];
  hbuf[0][t] = 0.f;
  float h_own = 0.f;
  float xr, xz, xn;
  if (L > 0 || b_ih == nullptr) {
    const float* row = xw + (size_t)start * G3;
    xr = row[t]; xz = row[HH + t]; xn = row[2 * HH + t];
  } else {
    xr = b_ih[t]; xz = b_ih[HH + t]; xn = b_ih[2 * HH + t];
  }
  __syncthreads();
  for (int step = 0; step < Lr; ++step) {
    // prefetch next step's xw row (sequential, no chase)
    float pr = 0.f, pz = 0.f, pn = 0.f;
    if (step + 1 < Lr) {
      const float* row = xw + (size_t)(start + step + 1) * G3;
      pr = row[t]; pz = row[HH + t]; pn = row[2 * HH + t];
    }
    const float4* h4 = (const float4*)hbuf[step & 1];
    float ar = br, az = bz, an = bn;
#pragma unroll
    for (int q = 0; q < 32; ++q) {
      const float4 h = h4[q];
      ar += wr[q].x * h.x; az += wz[q].x * h.x; an += wn[q].x * h.x;
      ar += wr[q].y * h.y; az += wz[q].y * h.y; an += wn[q].y * h.y;
      ar += wr[q].z * h.z; az += wz[q].z * h.z; an += wn[q].z * h.z;
      ar += wr[q].w * h.w; az += wz[q].w * h.w; an += wn[q].w * h.w;
    }
    const float r = 1.f / (1.f + __expf(-(xr + ar)));
    const float z = 1.f / (1.f + __expf(-(xz + az)));
    float targ = xn + r * an;
    targ = fminf(fmaxf(targ, -15.f), 15.f);
    const float e2 = __expf(2.f * targ);
    const float n = (e2 - 1.f) / (e2 + 1.f);
    h_own = (1.f - z) * n + z * h_own;
    hbuf[(step + 1) & 1][t] = h_own;
    if (h_seq) h_seq[(size_t)(start + step) * HH + t] = h_own;
    xr = pr; xz = pz; xn = pn;
    __syncthreads();
  }
  if (h_final) h_final[(size_t)c * HH + t] = h_own;
}

// ---------------------------------------------------------------------------
// Kernel 7: one wave per sentence -> scores[i] = tanh(scale * dot + b)
// ---------------------------------------------------------------------------
__global__ __launch_bounds__(256) void score_k(const float* __restrict__ sent,
                                               const int* __restrict__ labels,
                                               const float* __restrict__ ce,
                                               const float* __restrict__ lin_v,
                                               const float* __restrict__ scale,
                                               const float* __restrict__ lin_b,
                                               float* __restrict__ scores) {
  const int wid = threadIdx.x >> 6;
  const int lane = threadIdx.x & 63;
  const int i = blockIdx.x * 4 + wid;
  const float4* s4 = (const float4*)(sent + (size_t)i * DD);
  const float4* v4 = (const float4*)lin_v;
  const float4 a = s4[lane];
  const float4 b = v4[lane];
  float acc = a.x * b.x + a.y * b.y + a.z * b.z + a.w * b.w;
  if (lane < 32) {
    const float4* c4 = (const float4*)(ce + (size_t)labels[i] * HH);
    const float4 hh = c4[lane];
    const float4 vb = v4[64 + lane];
    acc += hh.x * vb.x + hh.y * vb.y + hh.z * vb.z + hh.w * vb.w;
  }
  for (int off = 32; off; off >>= 1) acc += __shfl_down(acc, off);
  if (lane == 0) scores[i] = tanhf(scale[0] * acc + lin_b[0]);
}

// ---------------------------------------------------------------------------
// Kernel 8: per-cluster score sums (one wave per cluster)
// ---------------------------------------------------------------------------
__global__ void clu_k(const float* __restrict__ scores,
                      const int* __restrict__ order,
                      const int* __restrict__ len,
                      float* __restrict__ clu) {
  const int c = blockIdx.x;
  const int lane = threadIdx.x;
  const int L = len[c];
  float acc = 0.f;
  for (int p = lane; p < L; p += 64) acc += scores[order[c * NN + p]];
  for (int off = 32; off; off >>= 1) acc += __shfl_down(acc, off);
  if (lane == 0) clu[c] = acc;
}

// ---------------------------------------------------------------------------
// Kernel 9: final blend with position scores
// ---------------------------------------------------------------------------
__global__ void final_k(const float* __restrict__ scores,
                        const int* __restrict__ labels,
                        const float* __restrict__ clu,
                        float* __restrict__ out) {
  const int i = blockIdx.x * blockDim.x + threadIdx.x;
  if (i >= NN) return;
  float ps = expf(-(float)(i + 1) * 0.0625f);   // 1/4096^(1/3) == 1/16
  ps = fmaxf(0.5f, ps);
  out[i] = 0.5f * (scores[i] / clu[labels[i]]) + 0.5f * ps;
}

// ---------------------------------------------------------------------------
extern "C" void kernel_launch(void* const* d_in, const int* in_sizes, int n_in,
                              void* d_out, int out_size, void* d_ws, size_t ws_size,
                              hipStream_t stream) {
  const float* sent   = (const float*)d_in[0];
  const int*   labels = (const int*)d_in[1];
  const float* W_ih0  = (const float*)d_in[2];
  const float* W_hh0  = (const float*)d_in[3];
  const float* b_ih0  = (const float*)d_in[4];
  const float* b_hh0  = (const float*)d_in[5];
  const float* W_ih1  = (const float*)d_in[6];
  const float* W_hh1  = (const float*)d_in[7];
  const float* b_ih1  = (const float*)d_in[8];
  const float* b_hh1  = (const float*)d_in[9];
  const float* lin_v  = (const float*)d_in[10];
  const float* lin_g  = (const float*)d_in[11];
  const float* lin_b  = (const float*)d_in[12];
  float* out = (float*)d_out;

  char* ws = (char*)d_ws;
  size_t off = 0;
  auto alloc = [&](size_t bytes) -> void* {
    void* p = ws + off;
    off = (off + bytes + 255) & ~(size_t)255;
    return p;
  };
  int*   order  = (int*)  alloc((size_t)KK * NN * sizeof(int));
  int*   pos    = (int*)  alloc(NN * sizeof(int));
  int*   len    = (int*)  alloc(KK * sizeof(int));
  int*   starts = (int*)  alloc((KK + 1) * sizeof(int));
  float* scale  = (float*)alloc(sizeof(float));
  float* xw     = (float*)alloc((size_t)(NN + KK) * G3 * sizeof(float));
  float* h1     = (float*)alloc((size_t)(NN + KK) * HH * sizeof(float));
  float* ce     = (float*)alloc((size_t)KK * HH * sizeof(float));
  float* scores = (float*)alloc(NN * sizeof(float));
  float* clu    = (float*)alloc(KK * sizeof(float));
  (void)ws_size; (void)in_sizes; (void)n_in; (void)out_size;

  build_order_k<<<dim3(KK + 1), dim3(64), 0, stream>>>(labels, lin_v, lin_g,
                                                       order, pos, len, scale);
  prefix_k<<<dim3(1), dim3(64), 0, stream>>>(len, starts);
  gemm_ih_k<DD><<<dim3(32, 6), dim3(256), 0, stream>>>(
      sent, W_ih0, b_ih0, labels, pos, starts, (const int*)nullptr, xw);
  gru_rec_k<<<dim3(KK), dim3(128), 0, stream>>>(
      xw, W_hh0, b_hh0, b_ih0, starts, len, h1, (float*)nullptr);
  gemm_ih_k<HH><<<dim3(33, 6), dim3(256), 0, stream>>>(
      h1, W_ih1, b_ih1, (const int*)nullptr, (const int*)nullptr,
      (const int*)nullptr, starts + KK, xw);
  gru_rec_k<<<dim3(KK), dim3(128), 0, stream>>>(
      xw, W_hh1, b_hh1, (const float*)nullptr, starts, len,
      (float*)nullptr, ce);
  score_k<<<dim3(NN / 4), dim3(256), 0, stream>>>(sent, labels, ce, lin_v,
                                                  scale, lin_b, scores);
  clu_k<<<dim3(KK), dim3(64), 0, stream>>>(scores, order, len, clu);
  final_k<<<dim3(16), dim3(256), 0, stream>>>(scores, labels, clu, out);
}

// Round 4
// 417.001 us; speedup vs baseline: 1.7157x; 1.7157x over previous
//
#include <hip/hip_runtime.h>
#include <cmath>

#define NN 4096
#define KK 32
#define DD 256
#define HH 128
#define G3 384   // 3*H

typedef __attribute__((ext_vector_type(8))) short short8;
typedef __attribute__((ext_vector_type(4))) float f32x4;

__device__ __forceinline__ unsigned short f2bf(float x) {
  unsigned int u = __float_as_uint(x);
  unsigned int r = (u + 0x7FFFu + ((u >> 16) & 1u)) >> 16;
  return (unsigned short)r;
}

// ---------------------------------------------------------------------------
// Kernel 1 (proven in R2): per-cluster ordered lists, positions, lengths;
// block KK computes the weight-norm scale g/||v||.
// ---------------------------------------------------------------------------
__global__ void build_order_k(const int* __restrict__ labels,
                              const float* __restrict__ lin_v,
                              const float* __restrict__ lin_g,
                              int* __restrict__ order,
                              int* __restrict__ pos,
                              int* __restrict__ len,
                              float* __restrict__ scale) {
  const int c = blockIdx.x;
  const int lane = threadIdx.x;
  if (c < KK) {
    int count = 0;
    for (int base = 0; base < NN; base += 64) {
      const int i = base + lane;
      const bool f = (labels[i] == c);
      const unsigned long long m = __ballot(f);
      if (f) {
        const int p = count + __popcll(m & ((1ull << lane) - 1ull));
        order[c * NN + p] = i;
        pos[i] = p;
      }
      count += __popcll(m);
    }
    if (lane == 0) len[c] = count;
  } else {
    float s = 0.f;
    for (int j = lane; j < G3; j += 64) { const float v = lin_v[j]; s += v * v; }
    for (int off = 32; off; off >>= 1) s += __shfl_down(s, off);
    if (lane == 0) scale[0] = lin_g[0] / sqrtf(s);
  }
}

// ---------------------------------------------------------------------------
// Kernel 2 (proven in R2): exclusive prefix over max(len,1) -> starts[KK+1]
// ---------------------------------------------------------------------------
__global__ void prefix_k(const int* __restrict__ len, int* __restrict__ starts) {
  if (threadIdx.x == 0) {
    int s = 0;
    for (int c = 0; c < KK; ++c) {
      starts[c] = s;
      const int l = len[c];
      s += (l > 0) ? l : 1;
    }
    starts[KK] = s;
  }
}

// ---------------------------------------------------------------------------
// Kernel 3: pack W_hh (both layers) into bf16 HI and LO-residual B-operand
// fragments of mfma_f32_16x16x32_bf16 (B = W_hh^T).
// Layout: [layer][half(hi=0,lo=1)][nt(24)][kt(4)][lane(64)][j(8)].
// B[k][n]: n = nt*16 + (lane&15), k = kt*32 + (lane>>4)*8 + j.
// ---------------------------------------------------------------------------
__global__ __launch_bounds__(256) void pack_whh_k(
    const float* __restrict__ W0, const float* __restrict__ W1,
    unsigned short* __restrict__ P) {
  const int gid = blockIdx.x * 256 + threadIdx.x;   // 2*2*24*4*64 = 24576
  if (gid >= 24576) return;
  const int lane = gid & 63;
  const int kt = (gid >> 6) & 3;
  const int nt = (gid >> 8) % 24;
  const int rest = (gid >> 8) / 24;                 // layer*2 + half
  const int half = rest & 1;
  const float* W = (rest >> 1) ? W1 : W0;
  const int n = nt * 16 + (lane & 15);
  const int kbase = kt * 32 + (lane >> 4) * 8;
  unsigned short* dst = P + (size_t)gid * 8;
#pragma unroll
  for (int j = 0; j < 8; ++j) {
    const float w = W[(size_t)n * HH + kbase + j];
    const unsigned short hi = f2bf(w);
    if (half == 0) {
      dst[j] = hi;
    } else {
      const float hif = __uint_as_float(((unsigned int)hi) << 16);
      dst[j] = f2bf(w - hif);
    }
  }
}

// ---------------------------------------------------------------------------
// Kernel 4/6 (proven in R2): out[slot(i)][g] = bias[g] + sum_d X[i][d]*W[g][d]
// BM=128 x BN=64, BK=16, 256 threads, 8x4 micro-tile.
// ---------------------------------------------------------------------------
template<int DIN>
__global__ __launch_bounds__(256) void gemm_ih_k(
    const float* __restrict__ X, const float* __restrict__ W,
    const float* __restrict__ bias,
    const int* __restrict__ labels, const int* __restrict__ pos,
    const int* __restrict__ starts, const int* __restrict__ Mtot,
    float* __restrict__ out) {
  __shared__ float Xs[16][132];
  __shared__ float Ws[16][68];
  const int M = Mtot ? *Mtot : NN;
  const int i0 = blockIdx.x * 128;
  const int g0 = blockIdx.y * 64;
  const int t  = threadIdx.x;
  const int it = t & 15;
  const int gt = t >> 4;
  float acc[8][4] = {};
  for (int k0 = 0; k0 < DIN; k0 += 16) {
#pragma unroll
    for (int l = 0; l < 2; ++l) {
      const int u = t * 2 + l;
      const int r = u >> 2;
      const int cq = u & 3;
      const int gi = i0 + r;
      float4 f = make_float4(0.f, 0.f, 0.f, 0.f);
      if (gi < M) f = *(const float4*)(X + (size_t)gi * DIN + k0 + cq * 4);
      Xs[cq * 4 + 0][r] = f.x; Xs[cq * 4 + 1][r] = f.y;
      Xs[cq * 4 + 2][r] = f.z; Xs[cq * 4 + 3][r] = f.w;
    }
    {
      const int r = t >> 2;
      const int cq = t & 3;
      const float4 f = *(const float4*)(W + (size_t)(g0 + r) * DIN + k0 + cq * 4);
      Ws[cq * 4 + 0][r] = f.x; Ws[cq * 4 + 1][r] = f.y;
      Ws[cq * 4 + 2][r] = f.z; Ws[cq * 4 + 3][r] = f.w;
    }
    __syncthreads();
#pragma unroll
    for (int k = 0; k < 16; ++k) {
      float a[8], b[4];
#pragma unroll
      for (int x = 0; x < 8; ++x) a[x] = Xs[k][it * 8 + x];
#pragma unroll
      for (int y = 0; y < 4; ++y) b[y] = Ws[k][gt * 4 + y];
#pragma unroll
      for (int x = 0; x < 8; ++x)
#pragma unroll
        for (int y = 0; y < 4; ++y)
          acc[x][y] += a[x] * b[y];
    }
    __syncthreads();
  }
  const float4 bs = *(const float4*)(bias + g0 + gt * 4);
#pragma unroll
  for (int x = 0; x < 8; ++x) {
    const int gi = i0 + it * 8 + x;
    if (gi >= M) continue;
    const int slot = labels ? (starts[labels[gi]] + pos[gi]) : gi;
    float4 o;
    o.x = acc[x][0] + bs.x; o.y = acc[x][1] + bs.y;
    o.z = acc[x][2] + bs.z; o.w = acc[x][3] + bs.w;
    *(float4*)(out + (size_t)slot * G3 + g0 + gt * 4) = o;
  }
}

// ---------------------------------------------------------------------------
// Kernel 5/7: GRU recurrence via MFMA. One block (4 waves) per cluster.
// hw = W_hh.h with D = A.B: A row0 = h_hi, row1 = h_lo (bf16 split of h).
// Two B chains per n-tile: W_hi (rows 0+1 used) and W_lo (row 0 used) ->
// hw = W_hi.(h_hi+h_lo) + W_lo.h_hi  (quantization error ~2^-17).
// hw and hpack are DOUBLE-BUFFERED by step parity: adjacent steps never
// touch the same LDS words (any write-overtakes-read hazard is 2 barriers
// away by construction). 2 barriers/step; xw prefetched 1 step ahead.
// ---------------------------------------------------------------------------
__global__ __launch_bounds__(256, 1) void gru_rec_mfma_k(
    const float* __restrict__ xw,              // sorted [Mtot][384] fp32
    const unsigned short* __restrict__ packHi, // this layer's W_hh^T hi frags
    const unsigned short* __restrict__ packLo, // lo-residual frags
    const float* __restrict__ b_hh,
    const float* __restrict__ b_ih,            // empty-cluster fallback or null
    const int* __restrict__ starts, const int* __restrict__ len,
    float* __restrict__ h_seq,                 // sorted [Mtot][128] or null
    float* __restrict__ h_final) {             // [KK][128] or null
  const int c = blockIdx.x;
  const int t = threadIdx.x;
  const int wv = t >> 6, lane = t & 63;
  // preload B fragments: wave wv owns n-tiles wv*6 .. wv*6+5
  short8 Bh[6][4], Bl[6][4];
#pragma unroll
  for (int i = 0; i < 6; ++i) {
    const int nt = wv * 6 + i;
#pragma unroll
    for (int kt = 0; kt < 4; ++kt) {
      const size_t idx = ((size_t)(nt * 4 + kt) * 64 + lane) * 8;
      Bh[i][kt] = *(const short8*)(packHi + idx);
      Bl[i][kt] = *(const short8*)(packLo + idx);
    }
  }
  const int L = len[c], start = starts[c];
  const int Lr = (L > 0) ? L : 1;
  __shared__ __align__(16) unsigned short hpack[2][2][HH]; // [parity][hi/lo]
  __shared__ float hw[2][G3];                              // [parity]
  if (t < HH) { hpack[0][0][t] = 0; hpack[0][1][t] = 0; }
  float br = 0.f, bz = 0.f, bn = 0.f, h_own = 0.f, xr = 0.f, xz = 0.f, xn = 0.f;
  if (t < HH) {
    br = b_hh[t]; bz = b_hh[HH + t]; bn = b_hh[2 * HH + t];
    if (L > 0 || b_ih == nullptr) {
      const float* row = xw + (size_t)start * G3;
      xr = row[t]; xz = row[HH + t]; xn = row[2 * HH + t];
    } else {
      xr = b_ih[t]; xz = b_ih[HH + t]; xn = b_ih[2 * HH + t];
    }
  }
  __syncthreads();
  const int q = lane >> 4;
  const int is_row0 = ((lane & 15) == 0) ? 0 : 1;   // row0 -> hi, others -> lo
  for (int step = 0; step < Lr; ++step) {
    const int par = step & 1;
    // A fragments: row m = lane&15; row0 = h_hi, row1.. = h_lo
    const unsigned short* hbase = hpack[par][is_row0];
    short8 A[4];
#pragma unroll
    for (int kt = 0; kt < 4; ++kt)
      A[kt] = *(const short8*)(hbase + kt * 32 + q * 8);
    // prefetch next step's xw row (latency hides under MFMAs)
    float pr = 0.f, pz = 0.f, pn = 0.f;
    if (t < HH && step + 1 < Lr) {
      const float* row = xw + (size_t)(start + step + 1) * G3;
      pr = row[t]; pz = row[HH + t]; pn = row[2 * HH + t];
    }
#pragma unroll
    for (int i = 0; i < 6; ++i) {
      f32x4 aH = {0.f, 0.f, 0.f, 0.f};
      f32x4 aL = {0.f, 0.f, 0.f, 0.f};
#pragma unroll
      for (int kt = 0; kt < 4; ++kt) {
        aH = __builtin_amdgcn_mfma_f32_16x16x32_bf16(A[kt], Bh[i][kt], aH, 0, 0, 0);
        aL = __builtin_amdgcn_mfma_f32_16x16x32_bf16(A[kt], Bl[i][kt], aL, 0, 0, 0);
      }
      // D rows: aH[0]=W_hi.h_hi, aH[1]=W_hi.h_lo, aL[0]=W_lo.h_hi
      if (lane < 16) hw[par][(wv * 6 + i) * 16 + lane] = aH[0] + aH[1] + aL[0];
    }
    __syncthreads();
    if (t < HH) {
      const float ar = xr + br + hw[par][t];
      const float az = xz + bz + hw[par][HH + t];
      const float an = bn + hw[par][2 * HH + t];
      const float r = 1.f / (1.f + __expf(-ar));
      const float z = 1.f / (1.f + __expf(-az));
      float targ = xn + r * an;
      targ = fminf(fmaxf(targ, -15.f), 15.f);
      const float e2 = __expf(2.f * targ);
      const float n = (e2 - 1.f) / (e2 + 1.f);
      h_own = (1.f - z) * n + z * h_own;
      const unsigned short hi = f2bf(h_own);
      const float hif = __uint_as_float(((unsigned int)hi) << 16);
      hpack[par ^ 1][0][t] = hi;
      hpack[par ^ 1][1][t] = f2bf(h_own - hif);
      if (h_seq) h_seq[(size_t)(start + step) * HH + t] = h_own;
      xr = pr; xz = pz; xn = pn;
    }
    __syncthreads();
  }
  if (h_final && t < HH) h_final[(size_t)c * HH + t] = h_own;
}

// ---------------------------------------------------------------------------
// Kernel 8 (proven): one wave per sentence -> scores[i] = tanh(scale*dot + b)
// ---------------------------------------------------------------------------
__global__ __launch_bounds__(256) void score_k(const float* __restrict__ sent,
                                               const int* __restrict__ labels,
                                               const float* __restrict__ ce,
                                               const float* __restrict__ lin_v,
                                               const float* __restrict__ scale,
                                               const float* __restrict__ lin_b,
                                               float* __restrict__ scores) {
  const int wid = threadIdx.x >> 6;
  const int lane = threadIdx.x & 63;
  const int i = blockIdx.x * 4 + wid;
  const float4* s4 = (const float4*)(sent + (size_t)i * DD);
  const float4* v4 = (const float4*)lin_v;
  const float4 a = s4[lane];
  const float4 b = v4[lane];
  float acc = a.x * b.x + a.y * b.y + a.z * b.z + a.w * b.w;
  if (lane < 32) {
    const float4* c4 = (const float4*)(ce + (size_t)labels[i] * HH);
    const float4 hh = c4[lane];
    const float4 vb = v4[64 + lane];
    acc += hh.x * vb.x + hh.y * vb.y + hh.z * vb.z + hh.w * vb.w;
  }
  for (int off = 32; off; off >>= 1) acc += __shfl_down(acc, off);
  if (lane == 0) scores[i] = tanhf(scale[0] * acc + lin_b[0]);
}

// ---------------------------------------------------------------------------
// Kernel 9 (proven): per-cluster score sums (one wave per cluster)
// ---------------------------------------------------------------------------
__global__ void clu_k(const float* __restrict__ scores,
                      const int* __restrict__ order,
                      const int* __restrict__ len,
                      float* __restrict__ clu) {
  const int c = blockIdx.x;
  const int lane = threadIdx.x;
  const int L = len[c];
  float acc = 0.f;
  for (int p = lane; p < L; p += 64) acc += scores[order[c * NN + p]];
  for (int off = 32; off; off >>= 1) acc += __shfl_down(acc, off);
  if (lane == 0) clu[c] = acc;
}

// ---------------------------------------------------------------------------
// Kernel 10 (proven): final blend with position scores
// ---------------------------------------------------------------------------
__global__ void final_k(const float* __restrict__ scores,
                        const int* __restrict__ labels,
                        const float* __restrict__ clu,
                        float* __restrict__ out) {
  const int i = blockIdx.x * blockDim.x + threadIdx.x;
  if (i >= NN) return;
  float ps = expf(-(float)(i + 1) * 0.0625f);   // 1/4096^(1/3) == 1/16
  ps = fmaxf(0.5f, ps);
  out[i] = 0.5f * (scores[i] / clu[labels[i]]) + 0.5f * ps;
}

// ---------------------------------------------------------------------------
extern "C" void kernel_launch(void* const* d_in, const int* in_sizes, int n_in,
                              void* d_out, int out_size, void* d_ws, size_t ws_size,
                              hipStream_t stream) {
  const float* sent   = (const float*)d_in[0];
  const int*   labels = (const int*)d_in[1];
  const float* W_ih0  = (const float*)d_in[2];
  const float* W_hh0  = (const float*)d_in[3];
  const float* b_ih0  = (const float*)d_in[4];
  const float* b_hh0  = (const float*)d_in[5];
  const float* W_ih1  = (const float*)d_in[6];
  const float* W_hh1  = (const float*)d_in[7];
  const float* b_ih1  = (const float*)d_in[8];
  const float* b_hh1  = (const float*)d_in[9];
  const float* lin_v  = (const float*)d_in[10];
  const float* lin_g  = (const float*)d_in[11];
  const float* lin_b  = (const float*)d_in[12];
  float* out = (float*)d_out;

  char* ws = (char*)d_ws;
  size_t off = 0;
  auto alloc = [&](size_t bytes) -> void* {
    void* p = ws + off;
    off = (off + bytes + 255) & ~(size_t)255;
    return p;
  };
  int*   order  = (int*)  alloc((size_t)KK * NN * sizeof(int));
  int*   pos    = (int*)  alloc(NN * sizeof(int));
  int*   len    = (int*)  alloc(KK * sizeof(int));
  int*   starts = (int*)  alloc((KK + 1) * sizeof(int));
  float* scale  = (float*)alloc(sizeof(float));
  unsigned short* pack = (unsigned short*)alloc((size_t)24576 * 8 * sizeof(unsigned short));
  float* xw     = (float*)alloc((size_t)(NN + KK) * G3 * sizeof(float));
  float* h1     = (float*)alloc((size_t)(NN + KK) * HH * sizeof(float));
  float* ce     = (float*)alloc((size_t)KK * HH * sizeof(float));
  float* scores = (float*)alloc(NN * sizeof(float));
  float* clu    = (float*)alloc(KK * sizeof(float));
  (void)ws_size; (void)in_sizes; (void)n_in; (void)out_size;

  const size_t packH = (size_t)24 * 4 * 64 * 8;   // ushorts per (layer,half)

  build_order_k<<<dim3(KK + 1), dim3(64), 0, stream>>>(labels, lin_v, lin_g,
                                                       order, pos, len, scale);
  prefix_k<<<dim3(1), dim3(64), 0, stream>>>(len, starts);
  pack_whh_k<<<dim3(96), dim3(256), 0, stream>>>(W_hh0, W_hh1, pack);
  gemm_ih_k<DD><<<dim3(32, 6), dim3(256), 0, stream>>>(
      sent, W_ih0, b_ih0, labels, pos, starts, (const int*)nullptr, xw);
  gru_rec_mfma_k<<<dim3(KK), dim3(256), 0, stream>>>(
      xw, pack, pack + packH, b_hh0, b_ih0, starts, len, h1, (float*)nullptr);
  gemm_ih_k<HH><<<dim3(33, 6), dim3(256), 0, stream>>>(
      h1, W_ih1, b_ih1, (const int*)nullptr, (const int*)nullptr,
      (const int*)nullptr, starts + KK, xw);
  gru_rec_mfma_k<<<dim3(KK), dim3(256), 0, stream>>>(
      xw, pack + 2 * packH, pack + 3 * packH, b_hh1, (const float*)nullptr,
      starts, len, (float*)nullptr, ce);
  score_k<<<dim3(NN / 4), dim3(256), 0, stream>>>(sent, labels, ce, lin_v,
                                                  scale, lin_b, scores);
  clu_k<<<dim3(KK), dim3(64), 0, stream>>>(scores, order, len, clu);
  final_k<<<dim3(16), dim3(256), 0, stream>>>(scores, labels, clu, out);
}